// Round 8
// baseline (20.511 us; speedup 1.0000x reference)
//
#include <hip/hip_runtime.h>

constexpr int NE = 8;       // N_ELEMENT
constexpr int NL = 32;      // N_LINES
constexpr int MB = 512;     // MINIBATCH
constexpr int SN = 1024;    // SAMPLE_N
constexpr float KS   = 0.01f / 1024.0f;  // SAMPLE_CM / SAMPLE_N
constexpr float I0   = 100000.0f;        // PROBE_I0
constexpr float OUTS = 0.05f;            // DET_SOLID_ANGLE_RATIO * SIGNAL_ATT

// Key idea: w_j = [I0*exp(-KS*bex)] * exp(-KS*e_local_j). The local factor
// needs only the thread's own xp, so the WHOLE SA dot-product stream runs
// with no barrier in front of it; the block-exclusive scalar W is applied
// to the 32 per-thread accumulators after the single barrier at the end.
// One block per batch row b; 256 threads; thread t owns samples 4t..4t+3.
__global__ __launch_bounds__(256)
void ppm_kernel(const float* __restrict__ xp,   // [8][512][1024]
                const float* __restrict__ mu,   // [8]
                const float* __restrict__ fl,   // [32]
                const float* __restrict__ SA,   // [32][512*1024]
                float* __restrict__ out)        // [32*512 fl_signal | 512 trans]
{
    const int b    = blockIdx.x;
    const int t    = threadIdx.x;
    const int lane = t & 63;
    const int wv   = t >> 6;

    __shared__ float s_wave[4];
    __shared__ float s_acc[256 * 33];   // [thread][line], stride 33: conflict-free
    __shared__ float s_part[256];       // [group(8)][line(32)]

    const size_t sarow = (size_t)b * SN;

    // ---- 1) xp loads (oldest in vmcnt queue) ----
    float x[NE][4];
    #pragma unroll
    for (int e = 0; e < NE; ++e) {
        const float4 v = reinterpret_cast<const float4*>(
            xp + (size_t)e * (MB * SN) + sarow)[t];
        x[e][0] = v.x; x[e][1] = v.y; x[e][2] = v.z; x[e][3] = v.w;
    }

    // ---- 2) first SA batch issued immediately (independent of xp) ----
    float4 A[8], B[8];
    #pragma unroll
    for (int l = 0; l < 8; ++l) {
        A[l] = reinterpret_cast<const float4*>(SA + ((size_t)l << 19) + sarow)[t];
    }

    // ---- 3) local attenuation factors + fold into xw (needs xp only) ----
    float a0 = 0.f, a1 = 0.f, a2 = 0.f, a3 = 0.f;
    #pragma unroll
    for (int e = 0; e < NE; ++e) {
        const float m = mu[e];
        a0 = fmaf(m, x[e][0], a0);
        a1 = fmaf(m, x[e][1], a1);
        a2 = fmaf(m, x[e][2], a2);
        a3 = fmaf(m, x[e][3], a3);
    }
    const float e1 = a0, e2 = a0 + a1, e3 = e2 + a2;
    const float T  = e3 + a3;
    const float l1 = __expf(-KS * e1);
    const float l2 = __expf(-KS * e2);
    const float l3 = __expf(-KS * e3);
    #pragma unroll
    for (int e = 0; e < NE; ++e) {
        x[e][1] *= l1; x[e][2] *= l2; x[e][3] *= l3;   // x[e][0] *= 1
    }

    // ---- 4) wave scan of chunk totals (VALU/LDS only, no barrier yet) ----
    float incl = T;
    #pragma unroll
    for (int d = 1; d < 64; d <<= 1) {
        const float v = __shfl_up(incl, d, 64);
        if (lane >= d) incl += v;
    }
    if (lane == 63) s_wave[wv] = incl;

    // ---- 5) barrier-free SA stream, double-buffered 8-line batches ----
    float acc[NL];
    #pragma unroll
    for (int l = 0; l < 8; ++l) {
        B[l] = reinterpret_cast<const float4*>(SA + ((size_t)(8 + l) << 19) + sarow)[t];
    }
    #pragma unroll
    for (int l = 0; l < 8; ++l) {                      // consume lines 0..7
        const int e = l >> 2;
        acc[l] = x[e][0] * A[l].x + x[e][1] * A[l].y
               + x[e][2] * A[l].z + x[e][3] * A[l].w;
    }
    #pragma unroll
    for (int l = 0; l < 8; ++l) {
        A[l] = reinterpret_cast<const float4*>(SA + ((size_t)(16 + l) << 19) + sarow)[t];
    }
    #pragma unroll
    for (int l = 0; l < 8; ++l) {                      // consume lines 8..15
        const int e = 2 + (l >> 2);
        acc[8 + l] = x[e][0] * B[l].x + x[e][1] * B[l].y
                   + x[e][2] * B[l].z + x[e][3] * B[l].w;
    }
    #pragma unroll
    for (int l = 0; l < 8; ++l) {
        B[l] = reinterpret_cast<const float4*>(SA + ((size_t)(24 + l) << 19) + sarow)[t];
    }
    #pragma unroll
    for (int l = 0; l < 8; ++l) {                      // consume lines 16..23
        const int e = 4 + (l >> 2);
        acc[16 + l] = x[e][0] * A[l].x + x[e][1] * A[l].y
                    + x[e][2] * A[l].z + x[e][3] * A[l].w;
    }
    #pragma unroll
    for (int l = 0; l < 8; ++l) {                      // consume lines 24..31
        const int e = 6 + (l >> 2);
        acc[24 + l] = x[e][0] * B[l].x + x[e][1] * B[l].y
                    + x[e][2] * B[l].z + x[e][3] * B[l].w;
    }

    // ---- 6) single barrier; apply block-exclusive scalar; reduce ----
    __syncthreads();

    float woff = 0.f;
    #pragma unroll
    for (int w2 = 0; w2 < 4; ++w2) woff += (w2 < wv) ? s_wave[w2] : 0.f;
    const float bex = woff + (incl - T);
    const float W   = I0 * __expf(-KS * bex);

    if (t == 0) {
        out[NL * MB + b] = KS * (s_wave[0] + s_wave[1] + s_wave[2] + s_wave[3]);
    }

    #pragma unroll
    for (int l = 0; l < NL; ++l) s_acc[t * 33 + l] = W * acc[l];
    __syncthreads();

    // 256 partials per line -> 8 group partials
    {
        const int l = t & 31, g = t >> 5;
        float s = 0.f;
        #pragma unroll
        for (int j = 0; j < 32; ++j) s += s_acc[(g * 32 + j) * 33 + l];
        s_part[t] = s;   // t == g*32 + l
    }
    __syncthreads();

    if (t < 32) {
        float tot = 0.f;
        #pragma unroll
        for (int g2 = 0; g2 < 8; ++g2) tot += s_part[g2 * 32 + t];
        out[t * MB + b] = OUTS * fl[t] * tot;
    }
}

extern "C" void kernel_launch(void* const* d_in, const int* in_sizes, int n_in,
                              void* d_out, int out_size, void* d_ws, size_t ws_size,
                              hipStream_t stream) {
    const float* xp = (const float*)d_in[0];
    const float* mu = (const float*)d_in[1];
    const float* fl = (const float*)d_in[2];
    const float* SA = (const float*)d_in[3];
    float* out = (float*)d_out;
    ppm_kernel<<<MB, 256, 0, stream>>>(xp, mu, fl, SA, out);
}